// Round 11
// baseline (51.163 us; speedup 1.0000x reference)
//
#include <hip/hip_runtime.h>
#include <hip/hip_bf16.h>
#include <stdint.h>

// MoEDecoder: B=64,T=256,IN=256,HID=512,OUT=256,L=2,E=16,S=1
// R11 = R10 with the x-staging OOB fixed (2048 chunks, 32/row, exact bounds).
//   3 LDS staging buffers per wave (96KB), VMWAIT(2*LPS) steady state ->
//   stage issued at t-3..t-2, consumed at t (true ~2-iter L2 cover).
//   h at stride 512 + 16B-chunk XOR swizzle (chunk ^= row&7) on write+read.
//   lgkmcnt(0) guard before refill closes the WAR race on the recycled buf.

typedef __attribute__((ext_vector_type(8))) short bf16x8;
typedef __attribute__((ext_vector_type(4))) float f32x4;

#define VMWAIT(N) asm volatile("s_waitcnt vmcnt(" #N ")" ::: "memory")
#define LGKM0() asm volatile("s_waitcnt lgkmcnt(0)" ::: "memory")

static __device__ __forceinline__ uint16_t f2bf(float f) {
  union { float f; uint32_t u; } c; c.f = f;
  uint32_t r = (c.u + 0x7FFFu + ((c.u >> 16) & 1u)) >> 16;
  return (uint16_t)r;
}
static __device__ __forceinline__ float bf2f(uint16_t h) {
  union { uint32_t u; float f; } c; c.u = ((uint32_t)h) << 16;
  return c.f;
}

static __device__ __forceinline__ void glds16(const uint16_t* g, uint16_t* l) {
  __builtin_amdgcn_global_load_lds(
      (const __attribute__((address_space(1))) uint32_t*)g,
      (__attribute__((address_space(3))) uint32_t*)l, 16, 0, 0);
}

// h storage swizzle: (row,col) -> row*512 + ((col>>3 ^ (row&7))<<3) | (col&7)
static __device__ __forceinline__ int hidx(int row, int col) {
  return row * 512 + ((((col >> 3) ^ (row & 7)) << 3) | (col & 7));
}

// ---- merged pre-pass: Wc=Ws+Wr (bf16), Wi/Wo bf16, bc=bs+br ----
__global__ __launch_bounds__(256) void k_prep(
    const float* __restrict__ Ws, const float* __restrict__ Wr,
    const float* __restrict__ Wi, const float* __restrict__ Wo,
    const float* __restrict__ bs, const float* __restrict__ br,
    uint16_t* __restrict__ Wcb, uint16_t* __restrict__ Wib,
    uint16_t* __restrict__ Wob, float* __restrict__ bc) {
  int bid = blockIdx.x, tid = threadIdx.x;
  if (bid < 8192) {                       // combine_w: 2*16*512*512 / 4
    int i = bid * 256 + tid;
    int idx = i * 4;
    int l = idx >> 22;
    int within = idx & (262144 - 1);
    float4 a = *(const float4*)(Ws + l * 262144 + within);
    float4 b = *(const float4*)(Wr + idx);
    ushort4 o;
    o.x = f2bf(a.x + b.x); o.y = f2bf(a.y + b.y);
    o.z = f2bf(a.z + b.z); o.w = f2bf(a.w + b.w);
    ((ushort4*)Wcb)[i] = o;
  } else if (bid < 8320) {                // Wi: 512*256/4
    int i = (bid - 8192) * 256 + tid;
    float4 v = ((const float4*)Wi)[i];
    ushort4 o;
    o.x = f2bf(v.x); o.y = f2bf(v.y); o.z = f2bf(v.z); o.w = f2bf(v.w);
    ((ushort4*)Wib)[i] = o;
  } else if (bid < 8448) {                // Wo: 256*512/4
    int i = (bid - 8320) * 256 + tid;
    float4 v = ((const float4*)Wo)[i];
    ushort4 o;
    o.x = f2bf(v.x); o.y = f2bf(v.y); o.z = f2bf(v.z); o.w = f2bf(v.w);
    ((ushort4*)Wob)[i] = o;
  } else {                                // bc: 2*16*512
    int i = (bid - 8448) * 256 + tid;
    int l = i >> 13, j = i & 511;
    bc[i] = bs[l * 512 + j] + br[i];
  }
}

// ---- one GEMM phase, triple-buffered barrier-free K-loop ----
// C[64][NT] = h[64][KK] * W[NT][KK]^T (+bias)(+resid)(relu), in-place into h
// unless F32OUT. 8 waves; wave w owns cols [w*NC,(w+1)*NC), all 64 rows.
template <int NT, int KK, int RESID, int F32OUT>
static __device__ __forceinline__ void gemm_phase(
    const uint16_t* __restrict__ W, const float* __restrict__ bias,
    uint16_t* h, float* __restrict__ gout, uint16_t* lS) {
  constexpr int NSTEP = KK / 32;
  constexpr int NC = NT / 8;          // 64 or 32 cols per wave
  constexpr int NFRAG = NC / 16;      // 4 or 2
  constexpr int LPS = NFRAG;          // glds (1KB each) per stage

  const int tid = threadIdx.x;
  const int lane = tid & 63, wave = tid >> 6;
  const int lr = lane & 15, c0 = lane >> 4;
  const int rb = c0 * 4;
  const int hsw = lr & 7;             // h chunk-swizzle key for A-reads

  uint16_t* lw = lS + wave * 6144;    // private 12KB region (3 x <=4KB bufs)

  // staging: lane l covers local row l/4, 16B chunk; source chunk
  // XOR-swizzled so the ds_read side is spread (verified R4/R5).
  const int srow = lane >> 2;
  const int sch = (lane & 3) ^ ((lane >> 3) & 3);
  const uint16_t* wbase = W + (size_t)(wave * NC + srow) * KK + sch * 8;

  auto stage = [&](int buf, int t) {
    #pragma unroll
    for (int j = 0; j < LPS; j++)
      glds16(wbase + (size_t)j * 16 * KK + t * 32, lw + buf * 2048 + j * 512);
  };

  stage(0, 0);
  stage(1, 1);
  stage(2, 2);

  // acc init = bias (+ residual from h) — hides under first stage latency
  f32x4 acc[4][NFRAG];
  #pragma unroll
  for (int n = 0; n < NFRAG; n++) {
    const int col = wave * NC + n * 16 + lr;
    const float bv = bias[col];
    #pragma unroll
    for (int m = 0; m < 4; m++)
      #pragma unroll
      for (int r = 0; r < 4; r++) {
        float v = bv;
        if constexpr (RESID) v += bf2f(h[hidx(m * 16 + rb + r, col)]);
        acc[m][n][r] = v;
      }
  }

  const int bch = c0 ^ ((lr >> 1) & 3);
  const uint16_t* pB0 = lw + lr * 32 + bch * 8;

  bf16x8 a[2][4], b[2][NFRAG];

  auto frag_read = [&](int slot, int t) {   // slot, t compile-time static
    const int ch = ((((t << 2) | c0) ^ hsw) << 3);   // swizzled 16B chunk
    #pragma unroll
    for (int m = 0; m < 4; m++)
      a[slot][m] = *(const bf16x8*)(h + (m * 16 + lr) * 512 + ch);
    const uint16_t* pB = pB0 + (t % 3) * 2048;
    #pragma unroll
    for (int n = 0; n < NFRAG; n++)
      b[slot][n] = *(const bf16x8*)(pB + n * 512);
  };

  if constexpr (LPS == 4) { VMWAIT(8); } else { VMWAIT(4); }  // stage(0) done
  frag_read(0, 0);

  #pragma unroll
  for (int t = 0; t < NSTEP; t++) {
    const int cur = t & 1, nxt = cur ^ 1;
    if (t + 3 < NSTEP) {
      LGKM0();                        // reads of recycled buf retired
      stage(t % 3, t + 3);            // ~2-iter cover from issue to use
    }
    if (t + 1 < NSTEP) {
      if (t + 3 < NSTEP) {
        if constexpr (LPS == 4) { VMWAIT(8); } else { VMWAIT(4); }
      } else if (t + 2 < NSTEP) {
        if constexpr (LPS == 4) { VMWAIT(4); } else { VMWAIT(2); }
      } else {
        VMWAIT(0);
      }
      frag_read(nxt, t + 1);          // ds_read hides under MFMA(t)
    }
    __builtin_amdgcn_s_setprio(1);
    #pragma unroll
    for (int m = 0; m < 4; m++)
      #pragma unroll
      for (int n = 0; n < NFRAG; n++)
        acc[m][n] = __builtin_amdgcn_mfma_f32_16x16x32_bf16(
            a[cur][m], b[cur][n], acc[m][n], 0, 0, 0);
    __builtin_amdgcn_s_setprio(0);
  }

  // ---- epilogue ----
  if constexpr (F32OUT) {
    #pragma unroll
    for (int n = 0; n < NFRAG; n++) {
      const int col = wave * NC + n * 16 + lr;
      #pragma unroll
      for (int m = 0; m < 4; m++)
        #pragma unroll
        for (int r = 0; r < 4; r++)
          gout[(size_t)(m * 16 + rb + r) * 256 + col] = acc[m][n][r];
    }
  } else {
    __syncthreads();  // all waves done reading h (A + resid)
    #pragma unroll
    for (int n = 0; n < NFRAG; n++) {
      const int col = wave * NC + n * 16 + lr;
      #pragma unroll
      for (int m = 0; m < 4; m++)
        #pragma unroll
        for (int r = 0; r < 4; r++)
          h[hidx(m * 16 + rb + r, col)] = f2bf(fmaxf(acc[m][n][r], 0.0f));
    }
    __syncthreads();  // writes visible before next phase reads
  }
}

__global__ __launch_bounds__(512) void k_fused(
    const float* __restrict__ x, const int* __restrict__ route,
    const uint16_t* __restrict__ Wib, const float* __restrict__ bi,
    const uint16_t* __restrict__ Wcb, const float* __restrict__ bcb,
    const uint16_t* __restrict__ Wob, const float* __restrict__ bo,
    float* __restrict__ out) {
  __shared__ uint16_t h[64 * 512];      // 65,536 B (chunk-swizzled layout)
  __shared__ uint16_t lS[8 * 6144];     // 98,304 B   total 163,840 B = 160KiB

  const int tid = threadIdx.x;
  // XCD swizzle: XCD r (= bid%8) gets the 8 batches with batch%8==r
  // (4 slabs each) -> per-phase L2 weight set <= 4MB (fits).
  const int bid = blockIdx.x;
  const int r = bid & 7, q = bid >> 3;
  const int batch = (q >> 2) * 8 + r;   // 0..63
  const int bx = batch * 4 + (q & 3);   // slab id 0..255
  const int e = route[batch];

  // stage x slab f32 -> bf16 into h: 2048 bf16x8-chunks, 32 per 256-f32 row
  const float* gx = x + (size_t)bx * 16384;
  #pragma unroll
  for (int j = 0; j < 4; j++) {
    int cid = j * 512 + tid;            // chunk id, 0..2047
    int row = cid >> 5, ch = cid & 31;  // exact bounds: ch*8+8 <= 256
    const float* src = gx + row * 256 + ch * 8;
    float4 v0 = *(const float4*)(src);
    float4 v1 = *(const float4*)(src + 4);
    bf16x8 o;
    o[0] = (short)f2bf(v0.x); o[1] = (short)f2bf(v0.y);
    o[2] = (short)f2bf(v0.z); o[3] = (short)f2bf(v0.w);
    o[4] = (short)f2bf(v1.x); o[5] = (short)f2bf(v1.y);
    o[6] = (short)f2bf(v1.z); o[7] = (short)f2bf(v1.w);
    *(bf16x8*)(h + row * 512 + ((ch ^ (row & 7)) << 3)) = o;
  }
  __syncthreads();

  // proj: h = relu(x * Wi^T + bi)            N=512 K=256
  gemm_phase<512, 256, 0, 0>(Wib, bi, h, nullptr, lS);
  // layer 0: h = relu(h*Wc[0,e]^T + bc + h)  N=K=512
  gemm_phase<512, 512, 1, 0>(Wcb + (size_t)e * 262144, bcb + e * 512,
                             h, nullptr, lS);
  // layer 1
  gemm_phase<512, 512, 1, 0>(Wcb + (size_t)(16 + e) * 262144,
                             bcb + (16 + e) * 512, h, nullptr, lS);
  // out: f32 = h * Wo^T + bo                 N=256 K=512
  gemm_phase<256, 512, 0, 1>(Wob, bo, h, out + (size_t)bx * 16384, lS);
}

extern "C" void kernel_launch(void* const* d_in, const int* in_sizes, int n_in,
                              void* d_out, int out_size, void* d_ws, size_t ws_size,
                              hipStream_t stream) {
  const float* x     = (const float*)d_in[0];
  const int*   route = (const int*)d_in[1];
  const float* Wi    = (const float*)d_in[2];
  const float* bi    = (const float*)d_in[3];
  const float* Wr    = (const float*)d_in[4];
  const float* br    = (const float*)d_in[5];
  const float* Ws    = (const float*)d_in[6];
  const float* bs    = (const float*)d_in[7];
  const float* Wo    = (const float*)d_in[8];
  const float* bo    = (const float*)d_in[9];

  char* ws = (char*)d_ws;
  uint16_t* Wib = (uint16_t*)(ws);                  //    262,144 B
  uint16_t* Wcb = (uint16_t*)(ws + 262144);         // 16,777,216 B
  uint16_t* Wob = (uint16_t*)(ws + 17039360);       //    262,144 B
  float*    bc  = (float*)   (ws + 17301504);       //     65,536 B

  k_prep<<<8512, 256, 0, stream>>>(Ws, Wr, Wi, Wo, bs, br,
                                   Wcb, Wib, Wob, bc);
  k_fused<<<256, 512, 0, stream>>>(x, route, Wib, bi, Wcb, bc, Wob, bo,
                                   (float*)d_out);
}